// Round 14
// baseline (539.491 us; speedup 1.0000x reference)
//
#include <hip/hip_runtime.h>
#include <hip/hip_bf16.h>

#define N_TOK 4096
#define DIM   1024
#define NEXP  8
#define FDIM  4096

// ---- 256x256, 8 waves (2Mx4N), BK=64, 2 buffers, catalog minimum-2ph cadence ----
#define GBM 256
#define GBN 256
#define GBK 64
#define GTILE (GBM * GBK)   // 16384 elems = 32 KB per operand per buffer

typedef __attribute__((ext_vector_type(8))) short bf16x8;
typedef __attribute__((ext_vector_type(4))) float f32x4;

__device__ __forceinline__ unsigned short f2bf(float f) {
    unsigned u = __builtin_bit_cast(unsigned, f);
    u = (u + 0x7fffu + ((u >> 16) & 1u)) >> 16;
    return (unsigned short)u;
}

// exact-GELU via branch-free erf approx (A&S 7.1.26, |err_erf| < 1.5e-7 abs)
__device__ __forceinline__ float gelu_f(float v) {
    float x = v * 0.70710678118654752f;
    float ax = fabsf(x);
    float t = __builtin_amdgcn_rcpf(1.0f + 0.3275911f * ax);
    float poly = t * (0.254829592f + t * (-0.284496736f + t * (1.421413741f +
                 t * (-1.453152027f + t * 1.061405429f))));
    float e = __expf(-x * x);
    float er = copysignf(1.0f - poly * e, x);
    return 0.5f * v * (1.0f + er);
}

// async global->LDS, 16B per lane. LDS dest is wave-uniform base + lane*16.
__device__ __forceinline__ void gld16(const unsigned short* g, unsigned short* l) {
    __builtin_amdgcn_global_load_lds(
        (const __attribute__((address_space(1))) unsigned int*)g,
        (__attribute__((address_space(3))) unsigned int*)l, 16, 0, 0);
}

// transpose tile body: in [R][C] fp32 -> out [C][R] bf16, 64x64 at (r0,c0); t = 0..255
__device__ __forceinline__ void tr_tile(const float* in, unsigned short* out,
                                        int R, int C, int r0, int c0, float (*tl)[65], int t) {
    int lr = t >> 4, lc = (t & 15) * 4;
#pragma unroll
    for (int it = 0; it < 4; it++) {
        int r = lr + it * 16;
        float4 v = *(const float4*)(in + (size_t)(r0 + r) * C + c0 + lc);
        tl[lc + 0][r] = v.x; tl[lc + 1][r] = v.y; tl[lc + 2][r] = v.z; tl[lc + 3][r] = v.w;
    }
    __syncthreads();
    int orow = t >> 3, orr = (t & 7) * 8;
#pragma unroll
    for (int it = 0; it < 2; it++) {
        int oc = orow + it * 32;
        unsigned short o[8];
#pragma unroll
        for (int j = 0; j < 8; j++) o[j] = f2bf(tl[oc][orr + j]);
        *(int4*)(out + (size_t)(c0 + oc) * R + r0 + orr) = *(const int4*)o;
    }
}

// heterogeneous pure-BW kernel: [0,8192) W1 tiles, [8192,16384) W2 tiles,
// [16384,17408) router (4 waves/block; also writes xbf = bf16 copy of x).
__global__ __launch_bounds__(256) void tr12_router_kernel(
    const float* __restrict__ W1, unsigned short* __restrict__ w1t,
    const float* __restrict__ W2, unsigned short* __restrict__ w2t,
    const float* __restrict__ x, const float* __restrict__ Wr,
    unsigned short* __restrict__ xbf,
    int* __restrict__ tk_idx, float* __restrict__ tk_w, int* __restrict__ counts) {
    __shared__ __align__(16) float tl[64][65];
    int idx = blockIdx.x;
    if (idx < 8192) {   // W1: R=1024, C=4096 -> 64 cx * 16 ry per expert
        int e = idx >> 10, rem = idx & 1023;
        int cx = rem & 63, ry = rem >> 6;
        tr_tile(W1 + (size_t)e * DIM * FDIM, w1t + (size_t)e * DIM * FDIM,
                DIM, FDIM, ry * 64, cx * 64, tl, threadIdx.x);
        return;
    }
    if (idx < 16384) {  // W2: R=4096, C=1024 -> 16 cx * 64 ry per expert
        int id = idx - 8192;
        int e = id >> 10, rem = id & 1023;
        int cx = rem & 15, ry = rem >> 4;
        tr_tile(W2 + (size_t)e * DIM * FDIM, w2t + (size_t)e * DIM * FDIM,
                FDIM, DIM, ry * 64, cx * 64, tl, threadIdx.x);
        return;
    }
    // router: token n, one wave
    int n = (idx - 16384) * 4 + (threadIdx.x >> 6);
    int l = threadIdx.x & 63;
    float acc[8];
#pragma unroll
    for (int e = 0; e < 8; e++) acc[e] = 0.f;
    const float* xr = x + (size_t)n * DIM;
    unsigned short* xo = xbf + (size_t)n * DIM;
#pragma unroll 4
    for (int i = 0; i < 16; i++) {
        int d = i * 64 + l;
        float xv = xr[d];
        xo[d] = f2bf(xv);
        const float4* wr = (const float4*)(Wr + (size_t)d * 8);
        float4 w0 = wr[0], w1 = wr[1];
        acc[0] += xv * w0.x; acc[1] += xv * w0.y; acc[2] += xv * w0.z; acc[3] += xv * w0.w;
        acc[4] += xv * w1.x; acc[5] += xv * w1.y; acc[6] += xv * w1.z; acc[7] += xv * w1.w;
    }
#pragma unroll
    for (int off = 32; off >= 1; off >>= 1)
#pragma unroll
        for (int e = 0; e < 8; e++) acc[e] += __shfl_xor(acc[e], off);
    if (l == 0) {
        float mx = acc[0];
#pragma unroll
        for (int e = 1; e < 8; e++) mx = fmaxf(mx, acc[e]);
        float p[8], s = 0.f;
#pragma unroll
        for (int e = 0; e < 8; e++) { p[e] = expf(acc[e] - mx); s += p[e]; }
#pragma unroll
        for (int e = 0; e < 8; e++) p[e] /= s;
        int i0 = 0;
#pragma unroll
        for (int e = 1; e < 8; e++) if (p[e] > p[i0]) i0 = e;
        int i1 = (i0 == 0) ? 1 : 0;
#pragma unroll
        for (int e = 0; e < 8; e++) if (e != i0 && p[e] > p[i1]) i1 = e;
        float w0 = p[i0], w1 = p[i1], s2 = w0 + w1;
        w0 /= s2; w1 /= s2;
        tk_idx[2 * n] = i0; tk_idx[2 * n + 1] = i1;
        tk_w[2 * n] = w0;   tk_w[2 * n + 1] = w1;
        atomicAdd(&counts[i0], 1);
        atomicAdd(&counts[i1], 1);
    }
}

__global__ void scan_kernel(const int* __restrict__ counts, int* __restrict__ offs,
                            int* __restrict__ cursor) {
    if (threadIdx.x == 0 && blockIdx.x == 0) {
        int a = 0;
        for (int e = 0; e < NEXP; e++) { offs[e] = a; cursor[e] = a; a += counts[e]; }
        offs[NEXP] = a;
    }
}

__global__ void fill_kernel(const int* __restrict__ tk_idx, int* __restrict__ cursor,
                            int* __restrict__ perm, int* __restrict__ inv) {
    int n = blockIdx.x * blockDim.x + threadIdx.x;
    if (n >= N_TOK) return;
    int i0 = tk_idx[2 * n], i1 = tk_idx[2 * n + 1];
    int p0 = atomicAdd(&cursor[i0], 1);
    perm[p0] = 2 * n;
    inv[2 * n] = p0;
    int p1 = atomicAdd(&cursor[i1], 1);
    perm[p1] = 2 * n + 1;
    inv[2 * n + 1] = p1;
}

// ---------------- GEMM core: 256x256, catalog minimum-2ph cadence ----------------
// 512 thr = 8 waves (2M x 4N); wave out 128x64 = 8x4 16x16 frags; BK=64, 2 buffers.
// LDS [256 rows][64 k] bf16 per buffer (128B rows = 8x16B blocks). 128 KB total.
// Swizzle (r7-verified, conflicts=0): phys 16B-block = logical ^ (row&7);
// inverse on per-lane GLOBAL source; linear global_load_lds dest.
// Iter: STAGE(next buf) | ds_read(cur)+64 MFMA (compiler-ordered lgkm) |
//       vmcnt(0) (free: loads had the whole MFMA cluster) | ONE barrier.
// AROW_PTR_: expression over `ra` giving the A-row base pointer (permuted A).

#define MFMA_(A_, B_, C_) __builtin_amdgcn_mfma_f32_16x16x32_bf16(A_, B_, C_, 0, 0, 0)

#define GEMM_CORE(K_, NT_, AROW_PTR_, B_)                                               \
    int t = threadIdx.x;                                                                \
    int lane = t & 63, wid = t >> 6;                                                    \
    int wr = wid >> 2, wc = wid & 3;                                                    \
    int arow_base = rt * GBM;                                                           \
    int srow8 = lane >> 3;                      /* row within 8-row chunk */            \
    int blog = (lane & 7) ^ srow8;              /* inverse-swizzled 16B block */        \
    const unsigned short* gA[4];                                                        \
    const unsigned short* gB[4];                                                        \
    _Pragma("unroll")                                                                   \
    for (int j = 0; j < 4; j++) {                                                       \
        int ra = min(arow_base + wid * 32 + j * 8 + srow8, cnt - 1);                    \
        gA[j] = (AROW_PTR_) + blog * 8;                                                 \
        gB[j] = B_ + (size_t)(n0 + wid * 32 + j * 8 + srow8) * K_ + blog * 8;           \
    }                                                                                   \
    f32x4 acc[8][4];                                                                    \
    _Pragma("unroll")                                                                   \
    for (int i = 0; i < 8; i++)                                                         \
        _Pragma("unroll")                                                               \
        for (int j = 0; j < 4; j++) acc[i][j] = (f32x4){0.f, 0.f, 0.f, 0.f};            \
    int rl = lane & 15;                                                                 \
    int kq = lane >> 4;                                                                 \
    int rx = rl & 7;                                                                    \
    auto stage = [&](int buf) {                                                         \
        unsigned short* la = As + buf * GTILE + (wid * 32) * GBK;                       \
        unsigned short* lb = Bs + buf * GTILE + (wid * 32) * GBK;                       \
        _Pragma("unroll")                                                               \
        for (int j = 0; j < 4; j++) {                                                   \
            gld16(gA[j], la + j * 8 * GBK); gA[j] += GBK;                               \
            gld16(gB[j], lb + j * 8 * GBK); gB[j] += GBK;                               \
        }                                                                               \
    };                                                                                  \
    auto compute = [&](int buf) {                                                       \
        const unsigned short* as = As + buf * GTILE;                                    \
        const unsigned short* bs = Bs + buf * GTILE;                                    \
        bf16x8 bfr[4][2];                                                               \
        _Pragma("unroll")                                                               \
        for (int nf = 0; nf < 4; nf++)                                                  \
            _Pragma("unroll")                                                           \
            for (int ks = 0; ks < 2; ks++)                                              \
                bfr[nf][ks] = *(const bf16x8*)(bs + (wc * 64 + nf * 16 + rl) * GBK      \
                                               + (((ks * 4 + kq) ^ rx) * 8));           \
        __builtin_amdgcn_s_setprio(1);                                                  \
        _Pragma("unroll")                                                               \
        for (int mf = 0; mf < 8; mf++) {                                                \
            bf16x8 a0 = *(const bf16x8*)(as + (wr * 128 + mf * 16 + rl) * GBK           \
                                         + ((kq ^ rx) * 8));                            \
            bf16x8 a1 = *(const bf16x8*)(as + (wr * 128 + mf * 16 + rl) * GBK           \
                                         + (((4 + kq) ^ rx) * 8));                      \
            _Pragma("unroll")                                                           \
            for (int nf = 0; nf < 4; nf++) acc[mf][nf] = MFMA_(a0, bfr[nf][0], acc[mf][nf]); \
            _Pragma("unroll")                                                           \
            for (int nf = 0; nf < 4; nf++) acc[mf][nf] = MFMA_(a1, bfr[nf][1], acc[mf][nf]); \
        }                                                                               \
        __builtin_amdgcn_s_setprio(0);                                                  \
    };                                                                                  \
    stage(0);                                                                           \
    asm volatile("s_waitcnt vmcnt(0)" ::: "memory");                                    \
    __builtin_amdgcn_s_barrier();                                                       \
    int cur = 0;                                                                        \
    for (int it = 0; it < NT_ - 1; ++it) {                                              \
        stage(cur ^ 1);                         /* issue next-tile loads FIRST */       \
        compute(cur);                           /* ds_read + 64 MFMA hide them */       \
        asm volatile("s_waitcnt vmcnt(0)" ::: "memory");                                \
        __builtin_amdgcn_s_barrier();           /* one barrier per K-tile */            \
        cur ^= 1;                                                                       \
    }                                                                                   \
    compute(cur);

// GEMM1: h = gelu(xb[perm] @ w1t^T)  (K=1024 -> NT=16, N=4096); grid 2048
__global__ __launch_bounds__(512) void gemm1_kernel(
    const unsigned short* __restrict__ xbf, const unsigned short* __restrict__ w1t,
    unsigned short* __restrict__ h, const int* __restrict__ counts, const int* __restrict__ offs,
    const int* __restrict__ perm) {
    __shared__ unsigned short As[2 * GTILE];
    __shared__ unsigned short Bs[2 * GTILE];
    // 16 rt x 16 nt x 8 e = 2048; XCD chunk (256) = one expert
    int L = blockIdx.x;
    int pos = (L & 7) * 256 + (L >> 3);
    int rt = pos & 15;
    int nt = (pos >> 4) & 15;
    int e = pos >> 8;
    int cnt = counts[e];
    if (rt * GBM >= cnt) return;
    int off = offs[e];
    int n0 = nt * GBN;
    const unsigned short* Bp = w1t + (size_t)e * FDIM * DIM;

    GEMM_CORE(DIM, 16,
              (xbf + (size_t)(perm[off + ra] >> 1) * DIM),
              Bp)

    int rq = lane >> 4;
#pragma unroll
    for (int mf = 0; mf < 8; mf++) {
#pragma unroll
        for (int r = 0; r < 4; r++) {
            int grow = arow_base + wr * 128 + mf * 16 + rq * 4 + r;
            if (grow < cnt) {
                unsigned short* hp = h + (size_t)(off + grow) * FDIM + n0 + wc * 64;
#pragma unroll
                for (int nf = 0; nf < 4; nf++)
                    hp[nf * 16 + rl] = f2bf(gelu_f(acc[mf][nf][r]));
            }
        }
    }
}

// GEMM2: ybuf = h @ w2t^T (K=4096 -> NT=64, N=1024); plain fp32 stores; grid 512
__global__ __launch_bounds__(512) void gemm2_kernel(
    const unsigned short* __restrict__ h, const unsigned short* __restrict__ w2t,
    float* __restrict__ ybuf, const int* __restrict__ counts, const int* __restrict__ offs) {
    __shared__ unsigned short As[2 * GTILE];
    __shared__ unsigned short Bs[2 * GTILE];
    // 16 rt x 4 nt x 8 e = 512; XCD chunk (64) = one expert
    int L = blockIdx.x;
    int pos = (L & 7) * 64 + (L >> 3);
    int rt = pos & 15;
    int nt = (pos >> 4) & 3;
    int e = pos >> 6;
    int cnt = counts[e];
    if (rt * GBM >= cnt) return;
    int off = offs[e];
    int n0 = nt * GBN;
    const unsigned short* Bp = w2t + (size_t)e * DIM * FDIM;

    GEMM_CORE(FDIM, 64,
              (h + (size_t)(off + ra) * FDIM),
              Bp)

    int rq = lane >> 4;
#pragma unroll
    for (int mf = 0; mf < 8; mf++) {
#pragma unroll
        for (int r = 0; r < 4; r++) {
            int grow = arow_base + wr * 128 + mf * 16 + rq * 4 + r;
            if (grow < cnt) {
                float* yp = ybuf + (size_t)(off + grow) * DIM + n0 + wc * 64;
#pragma unroll
                for (int nf = 0; nf < 4; nf++)
                    yp[nf * 16 + rl] = acc[mf][nf][r];
            }
        }
    }
}

// combine: out[n] = w0 * ybuf[inv[2n]] + w1 * ybuf[inv[2n+1]]; writes aux_loss = 0
__global__ __launch_bounds__(256) void combine_kernel(
    const float* __restrict__ ybuf, const int* __restrict__ inv,
    const float* __restrict__ tk_w, float* __restrict__ out) {
    int n = blockIdx.x;
    int d = threadIdx.x * 4;
    int p0 = inv[2 * n], p1 = inv[2 * n + 1];
    float w0 = tk_w[2 * n], w1 = tk_w[2 * n + 1];
    float4 a = *(const float4*)(ybuf + (size_t)p0 * DIM + d);
    float4 b = *(const float4*)(ybuf + (size_t)p1 * DIM + d);
    float4 o = {w0 * a.x + w1 * b.x, w0 * a.y + w1 * b.y,
                w0 * a.z + w1 * b.z, w0 * a.w + w1 * b.w};
    *(float4*)(out + (size_t)n * DIM + d) = o;
    if (n == 0 && threadIdx.x == 0) out[(size_t)N_TOK * DIM] = 0.f;  // aux_loss
}

extern "C" void kernel_launch(void* const* d_in, const int* in_sizes, int n_in,
                              void* d_out, int out_size, void* d_ws, size_t ws_size,
                              hipStream_t stream) {
    const float* x  = (const float*)d_in[0];
    const float* Wr = (const float*)d_in[1];
    const float* W1 = (const float*)d_in[2];
    const float* W2 = (const float*)d_in[3];
    float* out = (float*)d_out;

    char* w = (char*)d_ws;
    int*   counts = (int*)(w + 0);
    int*   offs   = (int*)(w + 64);
    int*   cursor = (int*)(w + 128);
    int*   tk_idx = (int*)(w + 256);
    float* tk_w   = (float*)(w + 256 + 32768);
    int*   perm   = (int*)(w + 256 + 65536);
    int*   inv    = (int*)(w + 256 + 131072);
    size_t base = (size_t)1 << 20;
    unsigned short* xbf  = (unsigned short*)(w + base);                       // 8 MB (bf16 x)
    unsigned short* hbuf = (unsigned short*)(w + base + ((size_t)16 << 20));  // 64 MB
    unsigned short* w1t  = (unsigned short*)(w + base + ((size_t)80 << 20));  // 64 MB (dead after gemm1)
    unsigned short* w2t  = (unsigned short*)(w + base + ((size_t)144 << 20)); // 64 MB
    float* ybuf = (float*)(w + base + ((size_t)80 << 20));                    // 32 MB, aliases w1t

    hipMemsetAsync(w, 0, 256, stream);

    // all pure-BW prep in one launch: W1 tiles (8192) + W2 tiles (8192) + router (1024)
    tr12_router_kernel<<<17408, 256, 0, stream>>>(W1, w1t, W2, w2t, x, Wr, xbf,
                                                  tk_idx, tk_w, counts);
    scan_kernel<<<1, 64, 0, stream>>>(counts, offs, cursor);
    fill_kernel<<<N_TOK / 256, 256, 0, stream>>>(tk_idx, cursor, perm, inv);

    gemm1_kernel<<<2048, 512, 0, stream>>>(xbf, w1t, hbuf, counts, offs, perm);
    gemm2_kernel<<<512, 512, 0, stream>>>(hbuf, w2t, ybuf, counts, offs);
    combine_kernel<<<N_TOK, 256, 0, stream>>>(ybuf, inv, tk_w, out);
}

// Round 15
// 463.995 us; speedup vs baseline: 1.1627x; 1.1627x over previous
//
#include <hip/hip_runtime.h>
#include <hip/hip_bf16.h>

#define N_TOK 4096
#define DIM   1024
#define NEXP  8
#define FDIM  4096

#define BM 128
#define BN 128
#define BK 32
#define TILE (BM * BK)   // elems per LDS tile buffer (8 KB)

typedef __attribute__((ext_vector_type(8))) short bf16x8;
typedef __attribute__((ext_vector_type(4))) float f32x4;

__device__ __forceinline__ unsigned short f2bf(float f) {
    unsigned u = __builtin_bit_cast(unsigned, f);
    u = (u + 0x7fffu + ((u >> 16) & 1u)) >> 16;
    return (unsigned short)u;
}

// exact-GELU via branch-free erf approx (A&S 7.1.26, |err_erf| < 1.5e-7 abs)
__device__ __forceinline__ float gelu_f(float v) {
    float x = v * 0.70710678118654752f;
    float ax = fabsf(x);
    float t = __builtin_amdgcn_rcpf(1.0f + 0.3275911f * ax);
    float poly = t * (0.254829592f + t * (-0.284496736f + t * (1.421413741f +
                 t * (-1.453152027f + t * 1.061405429f))));
    float e = __expf(-x * x);
    float er = copysignf(1.0f - poly * e, x);
    return 0.5f * v * (1.0f + er);
}

// async global->LDS, 16B per lane. LDS dest is wave-uniform base + lane*16.
__device__ __forceinline__ void gld16(const unsigned short* g, unsigned short* l) {
    __builtin_amdgcn_global_load_lds(
        (const __attribute__((address_space(1))) unsigned int*)g,
        (__attribute__((address_space(3))) unsigned int*)l, 16, 0, 0);
}

// small (64x64) transpose tile body: in [R][C] fp32 -> out [C][R] bf16 (for hidden W2 tr)
__device__ __forceinline__ void tr_tile(const float* in, unsigned short* out,
                                        int R, int C, int r0, int c0, float (*tl)[65]) {
    int t = threadIdx.x;
    int lr = t >> 4, lc = (t & 15) * 4;
#pragma unroll
    for (int it = 0; it < 4; it++) {
        int r = lr + it * 16;
        float4 v = *(const float4*)(in + (size_t)(r0 + r) * C + c0 + lc);
        tl[lc + 0][r] = v.x; tl[lc + 1][r] = v.y; tl[lc + 2][r] = v.z; tl[lc + 3][r] = v.w;
    }
    __syncthreads();
    int orow = t >> 3, orr = (t & 7) * 8;
#pragma unroll
    for (int it = 0; it < 2; it++) {
        int oc = orow + it * 32;
        unsigned short o[8];
#pragma unroll
        for (int j = 0; j < 8; j++) o[j] = f2bf(tl[oc][orr + j]);
        *(int4*)(out + (size_t)(c0 + oc) * R + r0 + orr) = *(const int4*)o;
    }
}

// heterogeneous: blocks [0,2048) = W1 transpose (128x128 tiles, bf16 LDS, big segments);
// blocks [2048,3072) = router (4 waves/block; also writes xbf = bf16 copy of x).
__global__ __launch_bounds__(256) void tr1_router_kernel(
    const float* __restrict__ W1, unsigned short* __restrict__ w1t,
    const float* __restrict__ x, const float* __restrict__ Wr,
    unsigned short* __restrict__ xbf,
    int* __restrict__ tk_idx, float* __restrict__ tk_w, int* __restrict__ counts) {
    __shared__ __align__(16) unsigned short tl[128][132];   // 33 KB, 264B rows (8B-aligned)
    int idx = blockIdx.x;
    int t = threadIdx.x;
    if (idx < 2048) {   // W1: [1024][4096] -> w1t [4096][1024]; 8 rt x 32 ct per expert
        int e = idx >> 8, rem = idx & 255;
        int ct = rem & 31, rt8 = rem >> 5;
        int r0 = rt8 * 128, c0 = ct * 128;
        const float* in = W1 + (size_t)e * DIM * FDIM;
        unsigned short* out = w1t + (size_t)e * DIM * FDIM;
        // phase 1: read 128x128 fp32 (8 rows x 512B per instr), cvt, b64 LDS writes
        int lr = t >> 5, lcq = (t & 31) * 4;
#pragma unroll
        for (int it = 0; it < 16; it++) {
            int r = lr + it * 8;
            float4 v = *(const float4*)(in + (size_t)(r0 + r) * FDIM + c0 + lcq);
            unsigned short o[4] = {f2bf(v.x), f2bf(v.y), f2bf(v.z), f2bf(v.w)};
            *(uint2*)&tl[r][lcq] = *(const uint2*)o;
        }
        __syncthreads();
        // phase 2: out-rows (cols of tile), 16 lanes x 16B = 256B contiguous per oc
        int rchunk = (t & 15) * 8;
#pragma unroll
        for (int it = 0; it < 8; it++) {
            int oc = (t >> 4) + it * 16;
            unsigned short o[8];
#pragma unroll
            for (int j = 0; j < 8; j++) o[j] = tl[rchunk + j][oc];
            *(int4*)(out + (size_t)(c0 + oc) * DIM + r0 + rchunk) = *(const int4*)o;
        }
        return;
    }
    // router: token n, one wave
    int n = (idx - 2048) * 4 + (t >> 6);
    int l = t & 63;
    float acc[8];
#pragma unroll
    for (int e = 0; e < 8; e++) acc[e] = 0.f;
    const float* xr = x + (size_t)n * DIM;
    unsigned short* xo = xbf + (size_t)n * DIM;
#pragma unroll 4
    for (int i = 0; i < 16; i++) {
        int d = i * 64 + l;
        float xv = xr[d];
        xo[d] = f2bf(xv);
        const float4* wr = (const float4*)(Wr + (size_t)d * 8);
        float4 w0 = wr[0], w1 = wr[1];
        acc[0] += xv * w0.x; acc[1] += xv * w0.y; acc[2] += xv * w0.z; acc[3] += xv * w0.w;
        acc[4] += xv * w1.x; acc[5] += xv * w1.y; acc[6] += xv * w1.z; acc[7] += xv * w1.w;
    }
#pragma unroll
    for (int off = 32; off >= 1; off >>= 1)
#pragma unroll
        for (int e = 0; e < 8; e++) acc[e] += __shfl_xor(acc[e], off);
    if (l == 0) {
        float mx = acc[0];
#pragma unroll
        for (int e = 1; e < 8; e++) mx = fmaxf(mx, acc[e]);
        float p[8], s = 0.f;
#pragma unroll
        for (int e = 0; e < 8; e++) { p[e] = expf(acc[e] - mx); s += p[e]; }
#pragma unroll
        for (int e = 0; e < 8; e++) p[e] /= s;
        int i0 = 0;
#pragma unroll
        for (int e = 1; e < 8; e++) if (p[e] > p[i0]) i0 = e;
        int i1 = (i0 == 0) ? 1 : 0;
#pragma unroll
        for (int e = 0; e < 8; e++) if (e != i0 && p[e] > p[i1]) i1 = e;
        float w0 = p[i0], w1 = p[i1], s2 = w0 + w1;
        w0 /= s2; w1 /= s2;
        tk_idx[2 * n] = i0; tk_idx[2 * n + 1] = i1;
        tk_w[2 * n] = w0;   tk_w[2 * n + 1] = w1;
        atomicAdd(&counts[i0], 1);
        atomicAdd(&counts[i1], 1);
    }
}

__global__ void scan_kernel(const int* __restrict__ counts, int* __restrict__ offs,
                            int* __restrict__ cursor) {
    if (threadIdx.x == 0 && blockIdx.x == 0) {
        int a = 0;
        for (int e = 0; e < NEXP; e++) { offs[e] = a; cursor[e] = a; a += counts[e]; }
        offs[NEXP] = a;
    }
}

__global__ void fill_kernel(const int* __restrict__ tk_idx, int* __restrict__ cursor,
                            int* __restrict__ perm, int* __restrict__ inv) {
    int n = blockIdx.x * blockDim.x + threadIdx.x;
    if (n >= N_TOK) return;
    int i0 = tk_idx[2 * n], i1 = tk_idx[2 * n + 1];
    int p0 = atomicAdd(&cursor[i0], 1);
    perm[p0] = 2 * n;
    inv[2 * n] = p0;
    int p1 = atomicAdd(&cursor[i1], 1);
    perm[p1] = 2 * n + 1;
    inv[2 * n + 1] = p1;
}

// ---------------- GEMM core (r5-exact, FROZEN): 3-buffer ring, 2-deep vmcnt(8), 2 barriers/iter ----------------
// Requires As/Bs (3*TILE ushorts each) in scope. 48 KB LDS -> 3 blocks/CU.
// Swizzle: phys 16B-block = logical_block ^ ((row>>1)&3); inverse on per-lane GLOBAL src, linear gld dest.
// AROW_PTR_: expression over `ra` yielding the A-row base pointer (enables permuted A).

#define GEMM_CORE(K_, NT_, AROW_PTR_, B_)                                               \
    int t = threadIdx.x;                                                                \
    int lane = t & 63, wid = t >> 6;                                                    \
    int wm = wid >> 1, wn = wid & 1;                                                    \
    int arow_base = rt * BM;                                                            \
    int srow = lane >> 2;                       /* row within 16-row segment */         \
    int logb = (lane & 3) ^ ((lane >> 3) & 3);  /* inverse-swizzled 16B block */        \
    const unsigned short* gA[2];                                                        \
    const unsigned short* gB[2];                                                        \
    _Pragma("unroll")                                                                   \
    for (int j = 0; j < 2; j++) {                                                       \
        int ra = min(arow_base + wid * 32 + j * 16 + srow, cnt - 1);                    \
        gA[j] = (AROW_PTR_) + logb * 8;                                                 \
        gB[j] = B_ + (size_t)(n0 + wid * 32 + j * 16 + srow) * K_ + logb * 8;           \
    }                                                                                   \
    f32x4 acc[4][4];                                                                    \
    _Pragma("unroll")                                                                   \
    for (int i = 0; i < 4; i++)                                                         \
        _Pragma("unroll")                                                               \
        for (int j = 0; j < 4; j++) acc[i][j] = (f32x4){0.f, 0.f, 0.f, 0.f};            \
    int rl = lane & 15;                                                                 \
    int kq = lane >> 4;                                                                 \
    int pb8 = (kq ^ ((rl >> 1) & 3)) * 8;       /* phys block offset for frag reads */  \
    auto stage = [&](int buf) {                                                         \
        unsigned short* la = As + buf * TILE + wid * 32 * BK;                           \
        unsigned short* lb = Bs + buf * TILE + wid * 32 * BK;                           \
        _Pragma("unroll")                                                               \
        for (int j = 0; j < 2; j++) { gld16(gA[j], la + j * 16 * BK); gA[j] += BK; }    \
        _Pragma("unroll")                                                               \
        for (int j = 0; j < 2; j++) { gld16(gB[j], lb + j * 16 * BK); gB[j] += BK; }    \
    };                                                                                  \
    auto compute = [&](int buf) {                                                       \
        const unsigned short* as = As + buf * TILE;                                     \
        const unsigned short* bs = Bs + buf * TILE;                                     \
        bf16x8 af[4], bfr[4];                                                           \
        _Pragma("unroll")                                                               \
        for (int mf = 0; mf < 4; mf++)                                                  \
            af[mf] = *(const bf16x8*)(as + (wm * 64 + mf * 16 + rl) * BK + pb8);        \
        _Pragma("unroll")                                                               \
        for (int nf = 0; nf < 4; nf++)                                                  \
            bfr[nf] = *(const bf16x8*)(bs + (wn * 64 + nf * 16 + rl) * BK + pb8);       \
        _Pragma("unroll")                                                               \
        for (int mf = 0; mf < 4; mf++)                                                  \
            _Pragma("unroll")                                                           \
            for (int nf = 0; nf < 4; nf++)                                              \
                acc[mf][nf] = __builtin_amdgcn_mfma_f32_16x16x32_bf16(                  \
                    af[mf], bfr[nf], acc[mf][nf], 0, 0, 0);                             \
    };                                                                                  \
    stage(0); stage(1);                                                                 \
    asm volatile("s_waitcnt vmcnt(4)" ::: "memory");  /* tile0 done, tile1 in flight */ \
    __builtin_amdgcn_s_barrier();                                                       \
    int cb = 0;                                                                         \
    for (int it = 0; it < NT_ - 2; ++it) {                                              \
        int sb = cb + 2; if (sb >= 3) sb -= 3;                                          \
        stage(sb);                                                                      \
        asm volatile("s_waitcnt vmcnt(8)" ::: "memory"); /* keep t+1,t+2 in flight */   \
        __builtin_amdgcn_s_barrier();                                                   \
        compute(cb);                                                                    \
        __builtin_amdgcn_s_barrier();                                                   \
        cb = cb + 1; if (cb >= 3) cb -= 3;                                              \
    }                                                                                   \
    asm volatile("s_waitcnt vmcnt(4)" ::: "memory");                                    \
    __builtin_amdgcn_s_barrier();                                                       \
    compute(cb);                                                                        \
    __builtin_amdgcn_s_barrier();                                                       \
    cb = cb + 1; if (cb >= 3) cb -= 3;                                                  \
    asm volatile("s_waitcnt vmcnt(0)" ::: "memory");                                    \
    __builtin_amdgcn_s_barrier();                                                       \
    compute(cb);

// heterogeneous: 16-block groups, sub 0-7 = gemm1 tiles (keeps b%8 XCD mapping),
// sub 8-15 = W2-transpose tiles (HBM-bound work hidden under latency-bound gemm1).
// gemm1 A-rows staged DIRECTLY from xbf via perm (per-lane global addresses).
__global__ __launch_bounds__(256) void gemm1_tr2_kernel(
    const unsigned short* __restrict__ xbf, const unsigned short* __restrict__ w1t,
    unsigned short* __restrict__ h, const int* __restrict__ counts, const int* __restrict__ offs,
    const int* __restrict__ perm,
    const float* __restrict__ W2, unsigned short* __restrict__ w2t) {
    __shared__ __align__(16) char shraw[3 * TILE * 2 * sizeof(unsigned short)];  // 48 KB
    int Lx = blockIdx.x;
    int grp = Lx >> 4, sub = Lx & 15;
    if (sub >= 8) {
        // W2 transpose: R=4096, C=1024 -> 16 cx * 64 ry per expert; id in [0,8192)
        int id = grp * 8 + (sub - 8);
        float (*tl)[65] = (float(*)[65])shraw;
        int e = id >> 10, rem = id & 1023;
        int cx = rem & 15, ry = rem >> 4;
        tr_tile(W2 + (size_t)e * DIM * FDIM, w2t + (size_t)e * DIM * FDIM,
                FDIM, DIM, ry * 64, cx * 64, tl);
        return;
    }
    unsigned short* As = (unsigned short*)shraw;
    unsigned short* Bs = As + 3 * TILE;
    int pos = sub * 1024 + grp;                 // XCD = sub (b%8), sequential within XCD
    const int NTX = N_TOK / BM;                 // 32
    const int NTY = FDIM / BN;                  // 32
    int rt = pos % NTX;
    int tmp = pos / NTX;
    int n0 = (tmp % NTY) * BN;
    int e = tmp / NTY;
    int cnt = counts[e];
    if (rt * BM >= cnt) return;
    int off = offs[e];
    const unsigned short* Bp = w1t + (size_t)e * FDIM * DIM;

    GEMM_CORE(DIM, 32,
              (xbf + (size_t)(perm[off + ra] >> 1) * DIM),
              Bp)

    int rq = lane >> 4;
#pragma unroll
    for (int mf = 0; mf < 4; mf++) {
#pragma unroll
        for (int r = 0; r < 4; r++) {
            int row_local = wm * 64 + mf * 16 + rq * 4 + r;
            int grow = arow_base + row_local;
            if (grow < cnt) {
                unsigned short* hp = h + (size_t)(off + grow) * FDIM + n0 + wn * 64;
#pragma unroll
                for (int nf = 0; nf < 4; nf++)
                    hp[nf * 16 + rl] = f2bf(gelu_f(acc[mf][nf][r]));
            }
        }
    }
}

// GEMM2: ybuf = h @ w2t^T (K=4096 -> NT=128, N=1024); plain fp32 stores
__global__ __launch_bounds__(256) void gemm2_kernel(
    const unsigned short* __restrict__ h, const unsigned short* __restrict__ w2t,
    float* __restrict__ ybuf, const int* __restrict__ counts, const int* __restrict__ offs) {
    __shared__ unsigned short As[3 * TILE];
    __shared__ unsigned short Bs[3 * TILE];
    // grid: 32 rt x 8 nt x 8 e = 2048; XCD chunk (256) = one expert
    int L = blockIdx.x;
    int pos = (L & 7) * 256 + (L >> 3);
    int rt = pos & 31;
    int nt = (pos >> 5) & 7;
    int e = pos >> 8;
    int cnt = counts[e];
    if (rt * BM >= cnt) return;
    int off = offs[e];
    int n0 = nt * BN;
    const unsigned short* Bp = w2t + (size_t)e * DIM * FDIM;

    GEMM_CORE(FDIM, 128,
              (h + (size_t)(off + ra) * FDIM),
              Bp)

    int rq = lane >> 4;
#pragma unroll
    for (int mf = 0; mf < 4; mf++) {
#pragma unroll
        for (int r = 0; r < 4; r++) {
            int row_local = wm * 64 + mf * 16 + rq * 4 + r;
            int grow = arow_base + row_local;
            if (grow < cnt) {
                float* yp = ybuf + (size_t)(off + grow) * DIM + n0 + wn * 64;
#pragma unroll
                for (int nf = 0; nf < 4; nf++)
                    yp[nf * 16 + rl] = acc[mf][nf][r];
            }
        }
    }
}

// combine: out[n] = w0 * ybuf[inv[2n]] + w1 * ybuf[inv[2n+1]]; also writes aux_loss = 0
__global__ __launch_bounds__(256) void combine_kernel(
    const float* __restrict__ ybuf, const int* __restrict__ inv,
    const float* __restrict__ tk_w, float* __restrict__ out) {
    int n = blockIdx.x;
    int d = threadIdx.x * 4;
    int p0 = inv[2 * n], p1 = inv[2 * n + 1];
    float w0 = tk_w[2 * n], w1 = tk_w[2 * n + 1];
    float4 a = *(const float4*)(ybuf + (size_t)p0 * DIM + d);
    float4 b = *(const float4*)(ybuf + (size_t)p1 * DIM + d);
    float4 o = {w0 * a.x + w1 * b.x, w0 * a.y + w1 * b.y,
                w0 * a.z + w1 * b.z, w0 * a.w + w1 * b.w};
    *(float4*)(out + (size_t)n * DIM + d) = o;
    if (n == 0 && threadIdx.x == 0) out[(size_t)N_TOK * DIM] = 0.f;  // aux_loss
}

extern "C" void kernel_launch(void* const* d_in, const int* in_sizes, int n_in,
                              void* d_out, int out_size, void* d_ws, size_t ws_size,
                              hipStream_t stream) {
    const float* x  = (const float*)d_in[0];
    const float* Wr = (const float*)d_in[1];
    const float* W1 = (const float*)d_in[2];
    const float* W2 = (const float*)d_in[3];
    float* out = (float*)d_out;

    char* w = (char*)d_ws;
    int*   counts = (int*)(w + 0);
    int*   offs   = (int*)(w + 64);
    int*   cursor = (int*)(w + 128);
    int*   tk_idx = (int*)(w + 256);
    float* tk_w   = (float*)(w + 256 + 32768);
    int*   perm   = (int*)(w + 256 + 65536);
    int*   inv    = (int*)(w + 256 + 131072);
    size_t base = (size_t)1 << 20;
    unsigned short* xbf  = (unsigned short*)(w + base);                       // 8 MB (bf16 x, token order)
    unsigned short* hbuf = (unsigned short*)(w + base + ((size_t)16 << 20));  // 64 MB
    unsigned short* w1t  = (unsigned short*)(w + base + ((size_t)80 << 20));  // 64 MB (dead after gemm1)
    unsigned short* w2t  = (unsigned short*)(w + base + ((size_t)144 << 20)); // 64 MB
    float* ybuf = (float*)(w + base + ((size_t)80 << 20));                    // 32 MB, aliases w1t

    hipMemsetAsync(w, 0, 256, stream);

    // W1 transpose (2048 big tiles) + router (1024 blocks x 4 tokens), one launch;
    // router also emits xbf (replaces the gather kernel).
    tr1_router_kernel<<<3072, 256, 0, stream>>>(W1, w1t, x, Wr, xbf, tk_idx, tk_w, counts);
    scan_kernel<<<1, 64, 0, stream>>>(counts, offs, cursor);
    fill_kernel<<<N_TOK / 256, 256, 0, stream>>>(tk_idx, cursor, perm, inv);

    // gemm1 (8192 tiles, A permuted on the fly) + W2 transpose (8192 tiles) fused
    gemm1_tr2_kernel<<<16384, 256, 0, stream>>>(xbf, w1t, hbuf, counts, offs, perm, W2, w2t);

    gemm2_kernel<<<32 * 8 * NEXP, 256, 0, stream>>>(hbuf, w2t, ybuf, counts, offs);
    combine_kernel<<<N_TOK, 256, 0, stream>>>(ybuf, inv, tk_w, out);
}